// Round 5
// baseline (73.173 us; speedup 1.0000x reference)
//
#include <hip/hip_runtime.h>

// Grouped conv: x (1,48,56,56) f32, w (24,96,7) f32, groups=2.
// y[o,h,wo] = sum_{i<24,k<7} x[24g+i, h, wo+k-3] * w[i, o%96, k]   (pad 3 on W)
// out[o,h,:] = y[o, (h - shift) mod 56, :]   (jnp.roll along H)
//
// R5: R4 structure, but L/R window float4s are no longer LOADED — they equal
// the M float4 of lane c4-1 / c4+1 in the same 16-lane row group, so they are
// synthesized with DPP row_shr:1 / row_shl:1 (VALU, in-register). Global loads
// per wave drop 72 -> 24. bound_ctrl:1 zeroes the row-edge lane => lz mask is
// free; rz cndmask kept (lane 13's shl pulls clamped lane-14 data). x-prefetch
// (depth 12) issued BEFORE weight staging so both cold-miss batches overlap
// ahead of the single barrier drain. FMA order identical to R2/R4.

#define Hh 56
#define Wd 56
#define HWsz (Hh * Wd)
#define CI 24
#define KW 7
#define OCB 4   // output channels per block (2 per wave)
#define PF 12   // prefetch depth in input channels

__device__ __forceinline__ float dpp_shr1(float v) {   // lane n <- lane n-1 (16-lane row), edge -> 0
    return __int_as_float(__builtin_amdgcn_update_dpp(
        0, __float_as_int(v), 0x111, 0xF, 0xF, true));
}
__device__ __forceinline__ float dpp_shl1(float v) {   // lane n <- lane n+1 (16-lane row), edge -> 0
    return __int_as_float(__builtin_amdgcn_update_dpp(
        0, __float_as_int(v), 0x101, 0xF, 0xF, true));
}

__global__ __launch_bounds__(128) void conv7_roll_kernel(
    const float* __restrict__ x,
    const float* __restrict__ w,
    const int* __restrict__ shift_p,
    float* __restrict__ out)
{
    const int tid  = threadIdx.x;
    const int wid  = tid >> 6;          // 0..1  -> oc pair within block
    const int lane = tid & 63;
    const int rl   = lane >> 4;         // 0..3  row within 4-row group
    const int c4r  = lane & 15;         // 0..15 (14,15 inactive)
    const int c4   = c4r < 13 ? c4r : 13;

    const int shift = shift_p[0];

    const int obase = blockIdx.x * OCB; // 0,4,...,188 (never straddles group)
    const int g     = obase / 96;
    const int ocb96 = obase - g * 96;

    const int h_out = blockIdx.y * 4 + rl;
    int hi = (h_out - shift) % Hh;
    if (hi < 0) hi += Hh;

    const float* xg = x + g * (CI * HWsz) + hi * Wd + c4 * 4;
    const bool rz = (c4 >= 13);

    // Issue the x prefetch batch FIRST so it overlaps the weight staging below.
    float4 Mb[PF];
    #pragma unroll
    for (int p = 0; p < PF; ++p)
        Mb[p] = *(const float4*)(xg + p * HWsz);

    // Stage weights: wl[oc_l][ci][8] (k=7 is pad)
    __shared__ __align__(16) float wl[OCB * CI * 8];
    for (int t = tid; t < OCB * CI * 8; t += 128) {
        const int oc_l = t / (CI * 8);
        const int rem  = t - oc_l * (CI * 8);
        const int ci   = rem >> 3;
        const int k    = rem & 7;
        wl[t] = (k < KW) ? w[ci * (96 * KW) + (ocb96 + oc_l) * KW + k] : 0.0f;
    }
    __syncthreads();

    const float* wl0 = &wl[(wid * 2    ) * (CI * 8)];
    const float* wl1 = &wl[(wid * 2 + 1) * (CI * 8)];

    float a0[4] = {0.f, 0.f, 0.f, 0.f};
    float a1[4] = {0.f, 0.f, 0.f, 0.f};

    #pragma unroll
    for (int ci = 0; ci < CI; ++ci) {
        const int s = ci % PF;          // compile-time after full unroll
        float4 M = Mb[s];
        if (ci + PF < CI)               // re-issue this slot for ci+PF
            Mb[s] = *(const float4*)(xg + (ci + PF) * HWsz);

        // L = M of lane c4-1 (edge lane auto-zeroed by bound_ctrl).
        float4 L, R;
        L.x = dpp_shr1(M.x); L.y = dpp_shr1(M.y);
        L.z = dpp_shr1(M.z); L.w = dpp_shr1(M.w);
        // R = M of lane c4+1; lanes 13..15 must see zero (lane 14 holds clamped data).
        R.x = dpp_shl1(M.x); R.y = dpp_shl1(M.y);
        R.z = dpp_shl1(M.z); R.w = dpp_shl1(M.w);
        if (rz) { R.x = 0.f; R.y = 0.f; R.z = 0.f; R.w = 0.f; }

        // Window cols 4c4-4 .. 4c4+7; output col 4c4+j uses xv[1+j+k].
        float xv[12] = {L.x, L.y, L.z, L.w, M.x, M.y, M.z, M.w, R.x, R.y, R.z, R.w};

        float4 wa = *(const float4*)(wl0 + ci * 8);
        float4 wb = *(const float4*)(wl0 + ci * 8 + 4);
        float4 wc = *(const float4*)(wl1 + ci * 8);
        float4 wd = *(const float4*)(wl1 + ci * 8 + 4);
        float w0[7] = {wa.x, wa.y, wa.z, wa.w, wb.x, wb.y, wb.z};
        float w1[7] = {wc.x, wc.y, wc.z, wc.w, wd.x, wd.y, wd.z};

        #pragma unroll
        for (int k = 0; k < KW; ++k) {
            #pragma unroll
            for (int j = 0; j < 4; ++j) {
                a0[j] += xv[1 + j + k] * w0[k];
                a1[j] += xv[1 + j + k] * w1[k];
            }
        }
    }

    if (c4r < 14) {
        const int o0 = obase + wid * 2;
        float* op0 = out + o0 * HWsz + h_out * Wd + c4 * 4;
        float* op1 = op0 + HWsz;
        *(float4*)op0 = make_float4(a0[0], a0[1], a0[2], a0[3]);
        *(float4*)op1 = make_float4(a1[0], a1[1], a1[2], a1[3]);
    }
}

extern "C" void kernel_launch(void* const* d_in, const int* in_sizes, int n_in,
                              void* d_out, int out_size, void* d_ws, size_t ws_size,
                              hipStream_t stream)
{
    const float* x     = (const float*)d_in[0];
    const float* w     = (const float*)d_in[1];
    const int*   shift = (const int*)d_in[2];
    float*       out   = (float*)d_out;

    dim3 grid(48, 14);   // 192/4 oc-groups x 56/4 row-groups
    conv7_roll_kernel<<<grid, 128, 0, stream>>>(x, w, shift, out);
}

// Round 6
// 65.858 us; speedup vs baseline: 1.1111x; 1.1111x over previous
//
#include <hip/hip_runtime.h>

// Grouped conv: x (1,48,56,56) f32, w (24,96,7) f32, groups=2.
// y[o,h,wo] = sum_{i<24,k<7} x[24g+i, h, wo+k-3] * w[i, o%96, k]   (pad 3 on W)
// out[o,h,:] = y[o, (h - shift) mod 56, :]   (jnp.roll along H)
//
// R6: R4 geometry (best measured, 67.7 us) with the LDS weight path deleted.
// Weights are wave-uniform (blockIdx + wave id), so they are read through the
// SCALAR path: readfirstlane(wid) makes the address uniform -> s_load into
// SGPRs; v_fmac reads the weight as an SGPR operand (free). This removes the
// staging loop, 96 ds_read_b128/wave, and the __syncthreads whose vmcnt(0)
// drain stalled the x-prefetch (R5's hidden cost). x path identical to R4:
// L/M/R float4 loads, depth-8 channel prefetch. FMA order unchanged.

#define Hh 56
#define Wd 56
#define HWsz (Hh * Wd)
#define CI 24
#define KW 7
#define OCB 4   // output channels per block (2 per wave)
#define PF 8    // prefetch depth in input channels

__global__ __launch_bounds__(128) void conv7_roll_kernel(
    const float* __restrict__ x,
    const float* __restrict__ w,
    const int* __restrict__ shift_p,
    float* __restrict__ out)
{
    const int tid  = threadIdx.x;
    const int wid  = __builtin_amdgcn_readfirstlane(tid >> 6); // wave-uniform in SGPR
    const int lane = tid & 63;
    const int rl   = lane >> 4;         // 0..3  row within 4-row group
    const int c4r  = lane & 15;         // 0..15 (14,15 inactive)
    const int c4   = c4r < 13 ? c4r : 13;

    const int shift = shift_p[0];

    const int obase = blockIdx.x * OCB; // 0,4,...,188 (never straddles group)
    const int g     = obase / 96;
    const int ocb96 = obase - g * 96;

    const int h_out = blockIdx.y * 4 + rl;
    int hi = (h_out - shift) % Hh;
    if (hi < 0) hi += Hh;

    // All loads stay inside row hi after clamping.
    const float* xg = x + g * (CI * HWsz) + hi * Wd + c4 * 4;
    const int dl = (c4 > 0  ? -4 : 0);
    const int dr = (c4 < 13 ?  4 : 0);
    const bool lz = (c4 == 0);
    const bool rz = (c4 >= 13);

    // Uniform weight base pointers for this wave's two output channels.
    const float* w0p = w + (ocb96 + wid * 2    ) * KW;
    const float* w1p = w + (ocb96 + wid * 2 + 1) * KW;

    float a0[4] = {0.f, 0.f, 0.f, 0.f};
    float a1[4] = {0.f, 0.f, 0.f, 0.f};

    // Prologue: issue loads for ci = 0..PF-1 (24 float4 in flight).
    float4 Mb[PF], Lb[PF], Rb[PF];
    #pragma unroll
    for (int p = 0; p < PF; ++p) {
        const float* b = xg + p * HWsz;
        Mb[p] = *(const float4*)b;
        Lb[p] = *(const float4*)(b + dl);
        Rb[p] = *(const float4*)(b + dr);
    }

    #pragma unroll
    for (int ci = 0; ci < CI; ++ci) {
        const int s = ci % PF;          // compile-time after full unroll
        float4 M = Mb[s];
        float4 L = Lb[s];
        float4 R = Rb[s];
        if (ci + PF < CI) {             // re-issue this slot for ci+PF
            const float* b = xg + (ci + PF) * HWsz;
            Mb[s] = *(const float4*)b;
            Lb[s] = *(const float4*)(b + dl);
            Rb[s] = *(const float4*)(b + dr);
        }
        if (lz) { L.x = 0.f; L.y = 0.f; L.z = 0.f; L.w = 0.f; }
        if (rz) { R.x = 0.f; R.y = 0.f; R.z = 0.f; R.w = 0.f; }
        // Window cols 4c4-4 .. 4c4+7; output col 4c4+j uses xv[1+j+k].
        float xv[12] = {L.x, L.y, L.z, L.w, M.x, M.y, M.z, M.w, R.x, R.y, R.z, R.w};

        // Wave-uniform weight reads -> s_load, broadcast via SGPR operands.
        float w0[KW], w1[KW];
        #pragma unroll
        for (int k = 0; k < KW; ++k) {
            w0[k] = w0p[ci * (96 * KW) + k];
            w1[k] = w1p[ci * (96 * KW) + k];
        }

        #pragma unroll
        for (int k = 0; k < KW; ++k) {
            #pragma unroll
            for (int j = 0; j < 4; ++j) {
                a0[j] += xv[1 + j + k] * w0[k];
                a1[j] += xv[1 + j + k] * w1[k];
            }
        }
    }

    if (c4r < 14) {
        const int o0 = obase + wid * 2;
        float* op0 = out + o0 * HWsz + h_out * Wd + c4 * 4;
        float* op1 = op0 + HWsz;
        *(float4*)op0 = make_float4(a0[0], a0[1], a0[2], a0[3]);
        *(float4*)op1 = make_float4(a1[0], a1[1], a1[2], a1[3]);
    }
}

extern "C" void kernel_launch(void* const* d_in, const int* in_sizes, int n_in,
                              void* d_out, int out_size, void* d_ws, size_t ws_size,
                              hipStream_t stream)
{
    const float* x     = (const float*)d_in[0];
    const float* w     = (const float*)d_in[1];
    const int*   shift = (const int*)d_in[2];
    float*       out   = (float*)d_out;

    dim3 grid(48, 14);   // 192/4 oc-groups x 56/4 row-groups
    conv7_roll_kernel<<<grid, 128, 0, stream>>>(x, w, shift, out);
}